// Round 1
// baseline (242.940 us; speedup 1.0000x reference)
//
#include <hip/hip_runtime.h>
#include <math.h>

#define B_ 64
#define N_ 8192
#define W_ 64
#define H_ 4
#define CTRL_ 280
#define EPS_ 1e-8f

__device__ __forceinline__ float softplusf(float x) {
    // stable: max(x,0) + log1p(exp(-|x|))
    return fmaxf(x, 0.f) + log1pf(expf(-fabsf(x)));
}

__device__ __forceinline__ float waveReduceSum(float v) {
    #pragma unroll
    for (int m = 1; m < 64; m <<= 1) v += __shfl_xor(v, m, 64);
    return v;
}

__device__ __forceinline__ float waveReduceMax(float v) {
    #pragma unroll
    for (int m = 1; m < 64; m <<= 1) v = fmaxf(v, __shfl_xor(v, m, 64));
    return v;
}

__device__ __forceinline__ float blockReduceSum256(float v, float* scr) {
    int t = threadIdx.x;
    v = waveReduceSum(v);
    if ((t & 63) == 0) scr[t >> 6] = v;
    __syncthreads();
    float r = scr[0] + scr[1] + scr[2] + scr[3];
    __syncthreads();
    return r;
}

__device__ __forceinline__ float blockReduceMax256(float v, float* scr) {
    int t = threadIdx.x;
    v = waveReduceMax(v);
    if ((t & 63) == 0) scr[t >> 6] = v;
    __syncthreads();
    float r = fmaxf(fmaxf(scr[0], scr[1]), fmaxf(scr[2], scr[3]));
    __syncthreads();
    return r;
}

// ---------------- K1: content-addressing scores -----------------------------
// grid (N/64, B), block 256. scores layout [B][H][N].
__global__ __launch_bounds__(256) void k_scores(const float* __restrict__ mem,
                                                const float* __restrict__ ctrl,
                                                float* __restrict__ scores) {
    __shared__ float tile[64 * 68];   // 64 rows x 64 cols, stride 68 (16B-aligned, 2-way max)
    __shared__ float keys[H_ * 68];
    __shared__ float knorm[H_];
    __shared__ float beta[H_];
    __shared__ float sstage[H_ * 65];

    const int t  = threadIdx.x;
    const int b  = blockIdx.y;
    const int n0 = blockIdx.x * 64;

    // keys (tanh) + per-head key norms; wave h handles head h
    {
        int h = t >> 6, w = t & 63;
        float kv = tanhf(ctrl[b * CTRL_ + h * W_ + w]);
        keys[h * 68 + w] = kv;
        float ss = waveReduceSum(kv * kv);
        if (w == 0) knorm[h] = sqrtf(ss);
        if (t < H_) beta[t] = softplusf(ctrl[b * CTRL_ + H_ * W_ + t]);
    }

    // stage 64x64 contiguous memory tile (16 KiB) coalesced
    const float4* gbase = reinterpret_cast<const float4*>(mem + ((size_t)b * N_ + n0) * W_);
    #pragma unroll
    for (int it = 0; it < 4; ++it) {
        int f = t + it * 256;          // float4 index within tile
        float4 v = gbase[f];
        int row = f >> 4, col = (f & 15) << 2;
        *reinterpret_cast<float4*>(&tile[row * 68 + col]) = v;
    }
    __syncthreads();

    // thread t: row = t/4, head = t%4 (row broadcast across 4 lanes)
    {
        int row = t >> 2, h = t & 3;
        float dot = 0.f, ss = 0.f;
        #pragma unroll
        for (int wg = 0; wg < 16; ++wg) {
            float4 mv = *reinterpret_cast<const float4*>(&tile[row * 68 + wg * 4]);
            float4 kv = *reinterpret_cast<const float4*>(&keys[h * 68 + wg * 4]);
            dot += mv.x * kv.x + mv.y * kv.y + mv.z * kv.z + mv.w * kv.w;
            ss  += mv.x * mv.x + mv.y * mv.y + mv.z * mv.z + mv.w * mv.w;
        }
        float sc = dot / (sqrtf(ss) * knorm[h] + EPS_) * beta[h];
        sstage[h * 65 + row] = sc;     // stride 65 breaks the 4-way bank alias
    }
    __syncthreads();

    // transpose-stage so global writes are wave-coalesced per head
    {
        int h = t >> 6, r = t & 63;
        scores[((size_t)(b * H_ + h)) * N_ + n0 + r] = sstage[h * 65 + r];
    }
}

// ---------------- K2: softmax -> interp -> circular conv -> sharpen ---------
// grid (B*H), block 256. Each thread owns 32 contiguous n.
__global__ __launch_bounds__(256) void k_weights(const float* __restrict__ scores,
                                                 const float* __restrict__ ctrl,
                                                 const float* __restrict__ prev,
                                                 float* __restrict__ wsharp,
                                                 float* __restrict__ Ssum) {
    __shared__ float scr[4];
    __shared__ float firsts[256];
    __shared__ float lasts[256];

    const int t  = threadIdx.x;
    const int bh = blockIdx.x;
    const int b  = bh >> 2;
    const int h  = bh & 3;

    // load this (b,h)'s 32 scores (per-thread contiguous, float4)
    const float4* sp = reinterpret_cast<const float4*>(scores + (size_t)bh * N_) + t * 8;
    float s[32];
    #pragma unroll
    for (int i = 0; i < 8; ++i) {
        float4 v = sp[i];
        s[i * 4 + 0] = v.x; s[i * 4 + 1] = v.y; s[i * 4 + 2] = v.z; s[i * 4 + 3] = v.w;
    }

    float mloc = -INFINITY;
    #pragma unroll
    for (int k = 0; k < 32; ++k) mloc = fmaxf(mloc, s[k]);
    float M = blockReduceMax256(mloc, scr);

    float eloc = 0.f;
    #pragma unroll
    for (int k = 0; k < 32; ++k) eloc += expf(s[k] - M);
    float L = blockReduceSum256(eloc, scr);
    float invL = 1.f / L;

    // prev weights
    const float4* pp = reinterpret_cast<const float4*>(prev + (size_t)bh * N_) + t * 8;
    float p[32];
    #pragma unroll
    for (int i = 0; i < 8; ++i) {
        float4 v = pp[i];
        p[i * 4 + 0] = v.x; p[i * 4 + 1] = v.y; p[i * 4 + 2] = v.z; p[i * 4 + 3] = v.w;
    }

    // control-derived scalars (redundant per thread; tiny, L2-hot)
    const float* cb = ctrl + b * CTRL_;
    float g  = 1.f / (1.f + expf(-cb[260 + h]));
    float r0 = cb[264 + 3 * h], r1 = cb[265 + 3 * h], r2 = cb[266 + 3 * h];
    float rm = fmaxf(r0, fmaxf(r1, r2));
    float e0 = expf(r0 - rm), e1 = expf(r1 - rm), e2 = expf(r2 - rm);
    float ers = 1.f / (e0 + e1 + e2);
    float s0f = e0 * ers, s1f = e1 * ers, s2f = e2 * ers;
    float gamma = 1.f + softplusf(cb[276 + h]);

    // interpolated weights
    float wi[32];
    #pragma unroll
    for (int k = 0; k < 32; ++k)
        wi[k] = g * (expf(s[k] - M) * invL) + (1.f - g) * p[k];

    // circular halo exchange (block covers the whole N ring)
    firsts[t] = wi[0];
    lasts[t]  = wi[31];
    __syncthreads();
    float wl = lasts[(t + 255) & 255];
    float wr = firsts[(t + 1) & 255];

    // conv + sharpen; write unnormalized, normalize in K3
    float4* wout = reinterpret_cast<float4*>(wsharp + (size_t)bh * N_) + t * 8;
    float su = 0.f;
    #pragma unroll
    for (int i = 0; i < 8; ++i) {
        float us[4];
        #pragma unroll
        for (int j = 0; j < 4; ++j) {
            int k = i * 4 + j;
            float left  = (k == 0)  ? wl : wi[k - 1];
            float right = (k == 31) ? wr : wi[k + 1];
            float wsv = s0f * left + s1f * wi[k] + s2f * right;
            float uv = powf(wsv, gamma);
            us[j] = uv;
            su += uv;
        }
        float4 o; o.x = us[0]; o.y = us[1]; o.z = us[2]; o.w = us[3];
        wout[i] = o;
    }
    float S = blockReduceSum256(su, scr);
    if (t == 0) Ssum[bh] = S;
}

// ---------------- K3: weighted read --------------------------------------
// grid (N/256, B), block 256. out must be zeroed before launch.
__global__ __launch_bounds__(256) void k_read(const float* __restrict__ mem,
                                              const float* __restrict__ wsh,
                                              const float* __restrict__ Ssum,
                                              float* __restrict__ out) {
    __shared__ float uLDS[H_ * 256];
    __shared__ float partial[16 * 64];

    const int t  = threadIdx.x;
    const int b  = blockIdx.y;
    const int cb = blockIdx.x * 256;

    // stage normalized weights for this 256-row chunk, all 4 heads
    {
        int h = t >> 6, i = (t & 63) << 2;
        float inv = 1.f / (Ssum[b * H_ + h] + EPS_);
        float4 v = *reinterpret_cast<const float4*>(&wsh[((size_t)(b * H_ + h)) * N_ + cb + i]);
        float4 u; u.x = v.x * inv; u.y = v.y * inv; u.z = v.z * inv; u.w = v.w * inv;
        *reinterpret_cast<float4*>(&uLDS[h * 256 + i]) = u;
    }
    __syncthreads();

    const int wv = t >> 6, l = t & 63;
    const int rb = wv * 64;                 // this wave's 64 rows within chunk
    float acc[4][4] = {};                   // acc[h][col within lane's float4]
    const float4* gb = reinterpret_cast<const float4*>(mem + ((size_t)b * N_ + cb) * W_);

    #pragma unroll 4
    for (int it = 0; it < 16; ++it) {
        int r  = rb + it * 4 + (l >> 4);    // 4 rows per wave-iter
        float4 mv = gb[(size_t)r * 16 + (l & 15)];   // 1 KiB contiguous per wave instr
        #pragma unroll
        for (int h = 0; h < 4; ++h) {
            float uh = uLDS[h * 256 + r];
            acc[h][0] += mv.x * uh; acc[h][1] += mv.y * uh;
            acc[h][2] += mv.z * uh; acc[h][3] += mv.w * uh;
        }
    }

    // reduce the 4 row-groups (lanes l, l^16, l^32, l^48)
    #pragma unroll
    for (int h = 0; h < 4; ++h) {
        #pragma unroll
        for (int j = 0; j < 4; ++j) {
            acc[h][j] += __shfl_xor(acc[h][j], 16, 64);
            acc[h][j] += __shfl_xor(acc[h][j], 32, 64);
        }
    }
    if (l < 16) {
        int c0 = l << 2;
        #pragma unroll
        for (int h = 0; h < 4; ++h)
            #pragma unroll
            for (int j = 0; j < 4; ++j)
                partial[(wv * 4 + h) * 64 + c0 + j] = acc[h][j];
    }
    __syncthreads();

    {
        int h = t >> 6, w = t & 63;
        float sum = partial[(0 * 4 + h) * 64 + w] + partial[(1 * 4 + h) * 64 + w]
                  + partial[(2 * 4 + h) * 64 + w] + partial[(3 * 4 + h) * 64 + w];
        atomicAdd(&out[(size_t)(b * H_ + h) * W_ + w], sum);
    }
}

extern "C" void kernel_launch(void* const* d_in, const int* in_sizes, int n_in,
                              void* d_out, int out_size, void* d_ws, size_t ws_size,
                              hipStream_t stream) {
    const float* mem  = (const float*)d_in[0];   // [B, N, W]
    const float* ctrl = (const float*)d_in[1];   // [B, 280]
    const float* prev = (const float*)d_in[2];   // [B, H, N]
    float* out = (float*)d_out;                  // [B, H, W] f32

    float* scores = (float*)d_ws;                               // 8 MiB
    float* wsharp = scores + (size_t)B_ * H_ * N_;              // 8 MiB
    float* ssum   = wsharp + (size_t)B_ * H_ * N_;              // 1 KiB

    hipMemsetAsync(d_out, 0, sizeof(float) * B_ * H_ * W_, stream);
    k_scores<<<dim3(N_ / 64, B_), 256, 0, stream>>>(mem, ctrl, scores);
    k_weights<<<dim3(B_ * H_), 256, 0, stream>>>(scores, ctrl, prev, wsharp, ssum);
    k_read<<<dim3(N_ / 256, B_), 256, 0, stream>>>(mem, wsharp, ssum, out);
}

// Round 2
// 239.389 us; speedup vs baseline: 1.0148x; 1.0148x over previous
//
#include <hip/hip_runtime.h>
#include <math.h>

#define B_ 64
#define N_ 8192
#define W_ 64
#define H_ 4
#define CTRL_ 280
#define EPS_ 1e-8f

__device__ __forceinline__ float softplusf(float x) {
    return fmaxf(x, 0.f) + log1pf(expf(-fabsf(x)));
}

__device__ __forceinline__ float waveReduceSum(float v) {
    #pragma unroll
    for (int m = 1; m < 64; m <<= 1) v += __shfl_xor(v, m, 64);
    return v;
}

__device__ __forceinline__ float blockReduceSum256(float v, float* scr) {
    int t = threadIdx.x;
    v = waveReduceSum(v);
    if ((t & 63) == 0) scr[t >> 6] = v;
    __syncthreads();
    float r = scr[0] + scr[1] + scr[2] + scr[3];
    __syncthreads();
    return r;
}

// ---------------- K1: content scores -> exp(score - beta) -------------------
// grid (N/64, B), block 256. expsc layout [B][H][N].
// softmax(s) == exp(s - beta)/sum(exp(s - beta)) since |s| <= beta (cos in
// [-1,1], beta = softplus >= 0): no separate max pass needed, no overflow.
__global__ __launch_bounds__(256) void k_scores(const float* __restrict__ mem,
                                                const float* __restrict__ ctrl,
                                                float* __restrict__ expsc) {
    __shared__ float tile[64 * 68];   // stride 68: 16B-aligned, <=2-way bank alias (free)
    __shared__ float keys[H_ * 68];
    __shared__ float knorm[H_];
    __shared__ float beta[H_];
    __shared__ float sstage[H_ * 65];

    const int t  = threadIdx.x;
    const int b  = blockIdx.y;
    const int n0 = blockIdx.x * 64;

    // keys (tanh) + per-head key norms; wave h handles head h
    {
        int h = t >> 6, w = t & 63;
        float kv = tanhf(ctrl[b * CTRL_ + h * W_ + w]);
        keys[h * 68 + w] = kv;
        float ss = waveReduceSum(kv * kv);
        if (w == 0) knorm[h] = sqrtf(ss);
        if (t < H_) beta[t] = softplusf(ctrl[b * CTRL_ + H_ * W_ + t]);
    }

    // stage 64x64 contiguous memory tile (16 KiB), coalesced 1 KiB/wave-instr
    const float4* gbase = reinterpret_cast<const float4*>(mem + ((size_t)b * N_ + n0) * W_);
    #pragma unroll
    for (int it = 0; it < 4; ++it) {
        int f = t + it * 256;
        float4 v = gbase[f];
        int row = f >> 4, col = (f & 15) << 2;
        *reinterpret_cast<float4*>(&tile[row * 68 + col]) = v;
    }
    __syncthreads();

    // thread t: row = t/4, head = t%4 (quad-broadcast LDS reads, conflict-free)
    {
        int row = t >> 2, h = t & 3;
        float dot = 0.f, ss = 0.f;
        #pragma unroll
        for (int wg = 0; wg < 16; ++wg) {
            float4 mv = *reinterpret_cast<const float4*>(&tile[row * 68 + wg * 4]);
            float4 kv = *reinterpret_cast<const float4*>(&keys[h * 68 + wg * 4]);
            dot += mv.x * kv.x + mv.y * kv.y + mv.z * kv.z + mv.w * kv.w;
            ss  += mv.x * mv.x + mv.y * mv.y + mv.z * mv.z + mv.w * mv.w;
        }
        float bh_ = beta[h];
        float sc = dot / (sqrtf(ss) * knorm[h] + EPS_) * bh_;
        sstage[h * 65 + row] = expf(sc - bh_);
    }
    __syncthreads();

    // coalesced per-head global writes
    {
        int h = t >> 6, r = t & 63;
        expsc[((size_t)(b * H_ + h)) * N_ + n0 + r] = sstage[h * 65 + r];
    }
}

// ---------------- K2: softmax-sum -> interp -> conv -> sharpen -> normalize -
// grid (B*H), block 256, 32 contiguous n per thread. Also zeroes d_out.
__global__ __launch_bounds__(256) void k_weights(const float* __restrict__ expsc,
                                                 const float* __restrict__ ctrl,
                                                 const float* __restrict__ prev,
                                                 float* __restrict__ wnorm,
                                                 float* __restrict__ out) {
    __shared__ float scr[4];
    __shared__ float firsts[256];
    __shared__ float lasts[256];

    const int t  = threadIdx.x;
    const int bh = blockIdx.x;
    const int b  = bh >> 2;
    const int h  = bh & 3;

    // zero this block's slice of d_out (stream order: completes before K3)
    if (t < 16) {
        float4 z = {0.f, 0.f, 0.f, 0.f};
        reinterpret_cast<float4*>(out + (size_t)bh * 64)[t] = z;
    }

    // load e = exp(score - beta), sum for softmax denominator
    const float4* sp = reinterpret_cast<const float4*>(expsc + (size_t)bh * N_) + t * 8;
    float a[32];
    float eloc = 0.f;
    #pragma unroll
    for (int i = 0; i < 8; ++i) {
        float4 v = sp[i];
        a[i * 4 + 0] = v.x; a[i * 4 + 1] = v.y; a[i * 4 + 2] = v.z; a[i * 4 + 3] = v.w;
        eloc += v.x + v.y + v.z + v.w;
    }
    float L = blockReduceSum256(eloc, scr);
    float invL = 1.f / L;

    // control-derived scalars (block-uniform, L2-hot)
    const float* cb = ctrl + b * CTRL_;
    float g  = 1.f / (1.f + expf(-cb[260 + h]));
    float r0 = cb[264 + 3 * h], r1 = cb[265 + 3 * h], r2 = cb[266 + 3 * h];
    float rm = fmaxf(r0, fmaxf(r1, r2));
    float e0 = expf(r0 - rm), e1 = expf(r1 - rm), e2 = expf(r2 - rm);
    float ers = 1.f / (e0 + e1 + e2);
    float s0f = e0 * ers, s1f = e1 * ers, s2f = e2 * ers;
    float gamma = 1.f + softplusf(cb[276 + h]);

    // interpolate with prev (overwrite a[] in place: wi)
    const float4* pp = reinterpret_cast<const float4*>(prev + (size_t)bh * N_) + t * 8;
    float wi[32];
    #pragma unroll
    for (int i = 0; i < 8; ++i) {
        float4 v = pp[i];
        #pragma unroll
        for (int j = 0; j < 4; ++j) {
            int k = i * 4 + j;
            float pv = (j == 0) ? v.x : (j == 1) ? v.y : (j == 2) ? v.z : v.w;
            wi[k] = g * (a[k] * invL) + (1.f - g) * pv;
        }
    }

    // circular halo (block covers the whole N ring)
    firsts[t] = wi[0];
    lasts[t]  = wi[31];
    __syncthreads();
    float wl = lasts[(t + 255) & 255];
    float wr = firsts[(t + 1) & 255];

    // conv + sharpen into a[] (unnormalized), accumulate S
    float su = 0.f;
    #pragma unroll
    for (int k = 0; k < 32; ++k) {
        float left  = (k == 0)  ? wl : wi[k - 1];
        float right = (k == 31) ? wr : wi[k + 1];
        float wsv = s0f * left + s1f * wi[k] + s2f * right;
        float uv = powf(wsv, gamma);
        a[k] = uv;
        su += uv;
    }
    float S = blockReduceSum256(su, scr);
    float invS = 1.f / (S + EPS_);

    // write normalized weights (float4, coalesced per-thread contiguous)
    float4* wout = reinterpret_cast<float4*>(wnorm + (size_t)bh * N_) + t * 8;
    #pragma unroll
    for (int i = 0; i < 8; ++i) {
        float4 o;
        o.x = a[i * 4 + 0] * invS; o.y = a[i * 4 + 1] * invS;
        o.z = a[i * 4 + 2] * invS; o.w = a[i * 4 + 3] * invS;
        wout[i] = o;
    }
}

// ---------------- K3: weighted read ----------------------------------------
// grid (N/256, B), block 256. out already zeroed by K2.
__global__ __launch_bounds__(256) void k_read(const float* __restrict__ mem,
                                              const float* __restrict__ wnorm,
                                              float* __restrict__ out) {
    __shared__ float uLDS[H_ * 256];
    __shared__ float partial[16 * 64];

    const int t  = threadIdx.x;
    const int b  = blockIdx.y;
    const int cb = blockIdx.x * 256;

    // stage this chunk's normalized weights, all 4 heads
    {
        int h = t >> 6, i = (t & 63) << 2;
        float4 v = *reinterpret_cast<const float4*>(&wnorm[((size_t)(b * H_ + h)) * N_ + cb + i]);
        *reinterpret_cast<float4*>(&uLDS[h * 256 + i]) = v;
    }
    __syncthreads();

    const int wv = t >> 6, l = t & 63;
    const int rb = wv * 64;
    float acc[4][4] = {};
    const float4* gb = reinterpret_cast<const float4*>(mem + ((size_t)b * N_ + cb) * W_);

    #pragma unroll 4
    for (int it = 0; it < 16; ++it) {
        int r  = rb + it * 4 + (l >> 4);
        float4 mv = gb[(size_t)r * 16 + (l & 15)];   // 1 KiB contiguous per wave instr
        #pragma unroll
        for (int h = 0; h < 4; ++h) {
            float uh = uLDS[h * 256 + r];            // 16-lane broadcast, conflict-free
            acc[h][0] += mv.x * uh; acc[h][1] += mv.y * uh;
            acc[h][2] += mv.z * uh; acc[h][3] += mv.w * uh;
        }
    }

    #pragma unroll
    for (int h = 0; h < 4; ++h) {
        #pragma unroll
        for (int j = 0; j < 4; ++j) {
            acc[h][j] += __shfl_xor(acc[h][j], 16, 64);
            acc[h][j] += __shfl_xor(acc[h][j], 32, 64);
        }
    }
    if (l < 16) {
        int c0 = l << 2;
        #pragma unroll
        for (int h = 0; h < 4; ++h)
            #pragma unroll
            for (int j = 0; j < 4; ++j)
                partial[(wv * 4 + h) * 64 + c0 + j] = acc[h][j];
    }
    __syncthreads();

    {
        int h = t >> 6, w = t & 63;
        float sum = partial[(0 * 4 + h) * 64 + w] + partial[(1 * 4 + h) * 64 + w]
                  + partial[(2 * 4 + h) * 64 + w] + partial[(3 * 4 + h) * 64 + w];
        atomicAdd(&out[(size_t)(b * H_ + h) * W_ + w], sum);
    }
}

extern "C" void kernel_launch(void* const* d_in, const int* in_sizes, int n_in,
                              void* d_out, int out_size, void* d_ws, size_t ws_size,
                              hipStream_t stream) {
    const float* mem  = (const float*)d_in[0];   // [B, N, W]
    const float* ctrl = (const float*)d_in[1];   // [B, 280]
    const float* prev = (const float*)d_in[2];   // [B, H, N]
    float* out = (float*)d_out;                  // [B, H, W] f32

    float* expsc = (float*)d_ws;                               // 8 MiB
    float* wnorm = expsc + (size_t)B_ * H_ * N_;               // 8 MiB

    k_scores <<<dim3(N_ / 64, B_), 256, 0, stream>>>(mem, ctrl, expsc);
    k_weights<<<dim3(B_ * H_), 256, 0, stream>>>(expsc, ctrl, prev, wnorm, out);
    k_read   <<<dim3(N_ / 256, B_), 256, 0, stream>>>(mem, wnorm, out);
}

// Round 3
// 238.251 us; speedup vs baseline: 1.0197x; 1.0048x over previous
//
#include <hip/hip_runtime.h>
#include <math.h>

#define B_ 64
#define N_ 8192
#define W_ 64
#define H_ 4
#define CTRL_ 280
#define EPS_ 1e-8f

__device__ __forceinline__ float softplusf(float x) {
    return fmaxf(x, 0.f) + log1pf(expf(-fabsf(x)));
}

__device__ __forceinline__ float waveReduceSum(float v) {
    #pragma unroll
    for (int m = 1; m < 64; m <<= 1) v += __shfl_xor(v, m, 64);
    return v;
}

template <int NW>
__device__ __forceinline__ float blockReduceSum(float v, float* scr) {
    int t = threadIdx.x;
    v = waveReduceSum(v);
    if ((t & 63) == 0) scr[t >> 6] = v;
    __syncthreads();
    float r = 0.f;
    #pragma unroll
    for (int i = 0; i < NW; ++i) r += scr[i];
    __syncthreads();
    return r;
}

// ---------------- K1: content scores -> exp(score - beta) -------------------
// grid (N/64, B), block 256. expsc layout [B][H][N].
// softmax(s) == exp(s - beta)/sum(exp(s - beta)) since |s| <= beta.
// No LDS tile: thread t owns row t>>2, head t&3; reads its row directly from
// global (quad-lane broadcast merges; 4 wg-iters share each 64B line via L1).
__global__ __launch_bounds__(256) void k_scores(const float* __restrict__ mem,
                                                const float* __restrict__ ctrl,
                                                float* __restrict__ expsc) {
    __shared__ float keys[H_ * 68];   // 272B/head: 16B-aligned, heads in distinct bank groups
    __shared__ float knorm[H_];
    __shared__ float beta[H_];
    __shared__ float sstage[H_ * 65];

    const int t  = threadIdx.x;
    const int b  = blockIdx.y;
    const int n0 = blockIdx.x * 64;

    // keys (tanh) + per-head key norms; wave h handles head h
    {
        int h = t >> 6, w = t & 63;
        float kv = tanhf(ctrl[b * CTRL_ + h * W_ + w]);
        keys[h * 68 + w] = kv;
        float ss = waveReduceSum(kv * kv);
        if (w == 0) knorm[h] = sqrtf(ss);
        if (t < H_) beta[t] = softplusf(ctrl[b * CTRL_ + H_ * W_ + t]);
    }
    __syncthreads();

    {
        int row = t >> 2, h = t & 3;
        const float4* mrow = reinterpret_cast<const float4*>(
            mem + ((size_t)b * N_ + n0 + row) * W_);
        const float4* krow = reinterpret_cast<const float4*>(&keys[h * 68]);
        float dot = 0.f, ss = 0.f;
        #pragma unroll
        for (int wg = 0; wg < 16; ++wg) {
            float4 mv = mrow[wg];            // global, L1-served after first touch
            float4 kv = krow[wg];            // LDS broadcast, conflict-free
            dot += mv.x * kv.x + mv.y * kv.y + mv.z * kv.z + mv.w * kv.w;
            ss  += mv.x * mv.x + mv.y * mv.y + mv.z * mv.z + mv.w * mv.w;
        }
        float bh_ = beta[h];
        float sc = dot / (sqrtf(ss) * knorm[h] + EPS_) * bh_;
        sstage[h * 65 + row] = expf(sc - bh_);
    }
    __syncthreads();

    // coalesced per-head global writes
    {
        int h = t >> 6, r = t & 63;
        expsc[((size_t)(b * H_ + h)) * N_ + n0 + r] = sstage[h * 65 + r];
    }
}

// ---------------- K2: softmax-sum -> interp -> conv -> sharpen -> normalize -
// grid (B*H), block 512, 16 contiguous n per thread. Also zeroes d_out.
__global__ __launch_bounds__(512) void k_weights(const float* __restrict__ expsc,
                                                 const float* __restrict__ ctrl,
                                                 const float* __restrict__ prev,
                                                 float* __restrict__ wnorm,
                                                 float* __restrict__ out) {
    __shared__ float scr[8];
    __shared__ float firsts[512];
    __shared__ float lasts[512];

    const int t  = threadIdx.x;
    const int bh = blockIdx.x;
    const int b  = bh >> 2;
    const int h  = bh & 3;

    // zero this block's slice of d_out (stream order: completes before K3)
    if (t < 16) {
        float4 z = {0.f, 0.f, 0.f, 0.f};
        reinterpret_cast<float4*>(out + (size_t)bh * 64)[t] = z;
    }

    // load e = exp(score - beta), sum for softmax denominator
    const float4* sp = reinterpret_cast<const float4*>(expsc + (size_t)bh * N_) + t * 4;
    float a[16];
    float eloc = 0.f;
    #pragma unroll
    for (int i = 0; i < 4; ++i) {
        float4 v = sp[i];
        a[i * 4 + 0] = v.x; a[i * 4 + 1] = v.y; a[i * 4 + 2] = v.z; a[i * 4 + 3] = v.w;
        eloc += v.x + v.y + v.z + v.w;
    }
    float L = blockReduceSum<8>(eloc, scr);
    float invL = 1.f / L;

    // control-derived scalars (block-uniform, L2-hot)
    const float* cb = ctrl + b * CTRL_;
    float g  = 1.f / (1.f + expf(-cb[260 + h]));
    float r0 = cb[264 + 3 * h], r1 = cb[265 + 3 * h], r2 = cb[266 + 3 * h];
    float rm = fmaxf(r0, fmaxf(r1, r2));
    float e0 = expf(r0 - rm), e1 = expf(r1 - rm), e2 = expf(r2 - rm);
    float ers = 1.f / (e0 + e1 + e2);
    float s0f = e0 * ers, s1f = e1 * ers, s2f = e2 * ers;
    float gamma = 1.f + softplusf(cb[276 + h]);

    // interpolate with prev
    const float4* pp = reinterpret_cast<const float4*>(prev + (size_t)bh * N_) + t * 4;
    float wi[16];
    #pragma unroll
    for (int i = 0; i < 4; ++i) {
        float4 v = pp[i];
        wi[i * 4 + 0] = g * (a[i * 4 + 0] * invL) + (1.f - g) * v.x;
        wi[i * 4 + 1] = g * (a[i * 4 + 1] * invL) + (1.f - g) * v.y;
        wi[i * 4 + 2] = g * (a[i * 4 + 2] * invL) + (1.f - g) * v.z;
        wi[i * 4 + 3] = g * (a[i * 4 + 3] * invL) + (1.f - g) * v.w;
    }

    // circular halo (block covers the whole N ring)
    firsts[t] = wi[0];
    lasts[t]  = wi[15];
    __syncthreads();
    float wl = lasts[(t + 511) & 511];
    float wr = firsts[(t + 1) & 511];

    // conv + sharpen into a[] (unnormalized), accumulate S
    float su = 0.f;
    #pragma unroll
    for (int k = 0; k < 16; ++k) {
        float left  = (k == 0)  ? wl : wi[k - 1];
        float right = (k == 15) ? wr : wi[k + 1];
        float wsv = s0f * left + s1f * wi[k] + s2f * right;
        float uv = powf(wsv, gamma);
        a[k] = uv;
        su += uv;
    }
    float S = blockReduceSum<8>(su, scr);
    float invS = 1.f / (S + EPS_);

    // write normalized weights (float4, coalesced per-thread contiguous)
    float4* wout = reinterpret_cast<float4*>(wnorm + (size_t)bh * N_) + t * 4;
    #pragma unroll
    for (int i = 0; i < 4; ++i) {
        float4 o;
        o.x = a[i * 4 + 0] * invS; o.y = a[i * 4 + 1] * invS;
        o.z = a[i * 4 + 2] * invS; o.w = a[i * 4 + 3] * invS;
        wout[i] = o;
    }
}

// ---------------- K3: weighted read ----------------------------------------
// grid (N/256, B), block 256. out already zeroed by K2.
__global__ __launch_bounds__(256) void k_read(const float* __restrict__ mem,
                                              const float* __restrict__ wnorm,
                                              float* __restrict__ out) {
    __shared__ float uLDS[H_ * 256];
    __shared__ float partial[16 * 64];

    const int t  = threadIdx.x;
    const int b  = blockIdx.y;
    const int cb = blockIdx.x * 256;

    // stage this chunk's normalized weights, all 4 heads
    {
        int h = t >> 6, i = (t & 63) << 2;
        float4 v = *reinterpret_cast<const float4*>(&wnorm[((size_t)(b * H_ + h)) * N_ + cb + i]);
        *reinterpret_cast<float4*>(&uLDS[h * 256 + i]) = v;
    }
    __syncthreads();

    const int wv = t >> 6, l = t & 63;
    const int rb = wv * 64;
    float acc[4][4] = {};
    const float4* gb = reinterpret_cast<const float4*>(mem + ((size_t)b * N_ + cb) * W_);

    #pragma unroll 4
    for (int it = 0; it < 16; ++it) {
        int r  = rb + it * 4 + (l >> 4);
        float4 mv = gb[(size_t)r * 16 + (l & 15)];   // 1 KiB contiguous per wave instr
        #pragma unroll
        for (int h = 0; h < 4; ++h) {
            float uh = uLDS[h * 256 + r];            // 16-lane broadcast, conflict-free
            acc[h][0] += mv.x * uh; acc[h][1] += mv.y * uh;
            acc[h][2] += mv.z * uh; acc[h][3] += mv.w * uh;
        }
    }

    #pragma unroll
    for (int h = 0; h < 4; ++h) {
        #pragma unroll
        for (int j = 0; j < 4; ++j) {
            acc[h][j] += __shfl_xor(acc[h][j], 16, 64);
            acc[h][j] += __shfl_xor(acc[h][j], 32, 64);
        }
    }
    if (l < 16) {
        int c0 = l << 2;
        #pragma unroll
        for (int h = 0; h < 4; ++h)
            #pragma unroll
            for (int j = 0; j < 4; ++j)
                partial[(wv * 4 + h) * 64 + c0 + j] = acc[h][j];
    }
    __syncthreads();

    {
        int h = t >> 6, w = t & 63;
        float sum = partial[(0 * 4 + h) * 64 + w] + partial[(1 * 4 + h) * 64 + w]
                  + partial[(2 * 4 + h) * 64 + w] + partial[(3 * 4 + h) * 64 + w];
        atomicAdd(&out[(size_t)(b * H_ + h) * W_ + w], sum);
    }
}

extern "C" void kernel_launch(void* const* d_in, const int* in_sizes, int n_in,
                              void* d_out, int out_size, void* d_ws, size_t ws_size,
                              hipStream_t stream) {
    const float* mem  = (const float*)d_in[0];   // [B, N, W]
    const float* ctrl = (const float*)d_in[1];   // [B, 280]
    const float* prev = (const float*)d_in[2];   // [B, H, N]
    float* out = (float*)d_out;                  // [B, H, W] f32

    float* expsc = (float*)d_ws;                               // 8 MiB
    float* wnorm = expsc + (size_t)B_ * H_ * N_;               // 8 MiB

    k_scores <<<dim3(N_ / 64, B_), 256, 0, stream>>>(mem, ctrl, expsc);
    k_weights<<<dim3(B_ * H_), 512, 0, stream>>>(expsc, ctrl, prev, wnorm, out);
    k_read   <<<dim3(N_ / 256, B_), 256, 0, stream>>>(mem, wnorm, out);
}